// Round 5
// baseline (211.469 us; speedup 1.0000x reference)
//
#include <hip/hip_runtime.h>

typedef _Float16 half_t;
typedef _Float16 half8 __attribute__((ext_vector_type(8)));
typedef _Float16 half4 __attribute__((ext_vector_type(4)));
typedef float f32x4 __attribute__((ext_vector_type(4)));

#define MFMA32(a, b, c) __builtin_amdgcn_mfma_f32_16x16x32_f16((a), (b), (c), 0, 0, 0)
#define MFMA16(a, b, c) __builtin_amdgcn_mfma_f32_16x16x16f16((a), (b), (c), 0, 0, 0)

static constexpr int kM  = 512;
static constexpr int kD  = 64;
static constexpr int kKL = 2560;
static constexpr int kL  = 2048;
// ws layout (halves): q_scaled | K f16 | V^T f16 [bh][d][k] | peT f16 [l][d]
static constexpr int WS_QS  = 0;                    // 1,048,576
static constexpr int WS_KB  = 1048576;              // 5,242,880
static constexpr int WS_VT  = WS_KB + 5242880;      // 5,242,880
static constexpr int WS_PET = WS_VT + 5242880;      // 131,072

// ---------- K1 (fused): q/k convert + V,pe transpose-convert ----------
__global__ __launch_bounds__(256) void prep_kernel(const float* __restrict__ q,
    const float* __restrict__ k, const float* __restrict__ v,
    const float* __restrict__ pe, half_t* __restrict__ ws) {
  __shared__ float ls[64 * 72];
  const int b = blockIdx.x, t = threadIdx.x;
  if (b < 3072) {
    const int i = b * 256 + t;
    const float QS = 0.125f * 1.4426950408889634f;  // 1/sqrt(64) * log2(e)
    const float* src; half_t* dst; float sc;
    if (i < 131072) { src = q + (size_t)i * 8; dst = ws + WS_QS + (size_t)i * 8; sc = QS; }
    else { const int j = i - 131072; src = k + (size_t)j * 8; dst = ws + WS_KB + (size_t)j * 8; sc = 1.0f; }
    const float4 a = ((const float4*)src)[0];
    const float4 bb = ((const float4*)src)[1];
    half_t tt[8];
    tt[0] = (half_t)(a.x * sc);  tt[1] = (half_t)(a.y * sc);
    tt[2] = (half_t)(a.z * sc);  tt[3] = (half_t)(a.w * sc);
    tt[4] = (half_t)(bb.x * sc); tt[5] = (half_t)(bb.y * sc);
    tt[6] = (half_t)(bb.z * sc); tt[7] = (half_t)(bb.w * sc);
    *(int4*)dst = *(int4*)tt;
    return;
  }
  const float* src; int sstride; half_t* dst; int dstride;
  if (b < 4352) {                       // V: 32 bh x 40 key-tiles -> Vt[bh][d][k]
    const int b2 = b - 3072;
    const int bh = b2 / 40, kt = b2 % 40;
    src = v + (size_t)(bh * 2560 + kt * 64) * 64; sstride = 64;
    dst = ws + WS_VT + (size_t)bh * 163840 + kt * 64; dstride = 2560;
  } else {                              // pe: [64][2048] -> peT[2048][64]
    const int b3 = b - 4352;
    src = pe + (size_t)b3 * 64; sstride = 2048;
    dst = ws + WS_PET + (size_t)b3 * 64 * 64; dstride = 64;
  }
  const int rr = t >> 4, cq = (t & 15) * 4;
#pragma unroll
  for (int p = 0; p < 4; ++p) {
    const float4 x = *(const float4*)(src + (size_t)(p * 16 + rr) * sstride + cq);
    *(float4*)(ls + (p * 16 + rr) * 72 + cq) = x;
  }
  __syncthreads();
  const int oc = t >> 2, ch = t & 3;
  half_t tmp[16];
#pragma unroll
  for (int i2 = 0; i2 < 16; ++i2) tmp[i2] = (half_t)ls[(ch * 16 + i2) * 72 + oc];
  half_t* o = dst + (size_t)oc * dstride + ch * 16;
  ((int4*)o)[0] = ((int4*)tmp)[0];
  ((int4*)o)[1] = ((int4*)tmp)[1];
}

// ---------- K2: fused banded attention, S^T orientation ----------
// grid = 1024 (bh x 16-row q-tile, XCD-swizzled), block = 512 (8 waves).
// S^T = K.Q^T via mfma 16x16x32 (A=K-frag, B=Q-frag): lane (c,qd) reg holds
// S^T[key=qd*4+reg][query m=c]. P stays IN REGISTERS as the B-frag of
// mfma_f32_16x16x16f16 for PV (O^T = V^T.P): no LDS round-trip for P.
// PE bias: PE^T windows MFMA'd ONE TILE AHEAD into a double-buffered LDS
// strip [48][18] f16 per wave (rows = l - (rel0-16)); softmax reads row
// qd*4+reg-c+16 (and +16). Window at lbase rel0+48 is dual-written (next
// buffer rows 32-47 AND current buffer rows 0-15 for t+2).
// K-frags prefetched one tile ahead in registers; V issued at top of iter.
__global__ __launch_bounds__(512, 4) void attn_kernel(
    const half_t* __restrict__ ws, const float* __restrict__ cvp,
    float* __restrict__ out) {

  __shared__ __align__(16) char smem[8 * 4416 + 1024];

  const int tid  = threadIdx.x;
  const int lane = tid & 63;
  const int w    = tid >> 6;
  const int c    = lane & 15;
  const int qd   = lane >> 4;

  const int id = blockIdx.x;
  const int bh = ((id & 7) << 2) | (id >> 8);   // XCD-aware: 4 bh per XCD
  const int mt = (id >> 3) & 31;
  const int m0 = mt << 4;

  const float cvl = cvp[bh & 7] * 2048.0f - 2047.0f;  // mask = clamp((l+cvl)/64+1,0,1)

  const half_t* kb   = ws + WS_KB + (size_t)bh * (kKL * kD);
  const half_t* vt   = ws + WS_VT + (size_t)bh * (kKL * kD);
  const half_t* pet  = ws + WS_PET;
  const half_t* qrow = ws + WS_QS + (size_t)(bh * kM + m0 + c) * kD;
  // Q as B-operand: lane (c,qd) holds Q[m=c][d=qd*8+j] — same bytes as A-frag.
  const half8 bq0 = *(const half8*)(qrow + qd * 8);
  const half8 bq1 = *(const half8*)(qrow + 32 + qd * 8);

  half_t* bias = (half_t*)(smem + w * 4416);   // 2 buffers x [48][18] f16 (864 halves each)

  float zal = 0.0f, zm = 0.0f;                 // per-lane, query m=c (dup x4 over qd)
  f32x4 o0 = {0,0,0,0}, o1 = {0,0,0,0}, o2 = {0,0,0,0}, o3 = {0,0,0,0};

  const int t0 = (w * 65) >> 3;
  const int t1 = ((w + 1) * 65) >> 3;

  // ---- PE window helper: C-layout PE^T[l-local=qd*4+reg][m=c] ----
  auto pe_window = [&](int lbase) -> f32x4 {
    int l = lbase + c;
    l = (l < 0) ? 0 : (l > kL - 1 ? kL - 1 : l);
    const half8 p0 = *(const half8*)(pet + (size_t)l * kD + qd * 8);
    const half8 p1 = *(const half8*)(pet + (size_t)l * kD + 32 + qd * 8);
    f32x4 acc = {0,0,0,0};
    acc = MFMA32(p0, bq0, acc);
    acc = MFMA32(p1, bq1, acc);
    return acc;
  };
  auto store_win = [&](int buf, int ro, const f32x4& pw) {
#pragma unroll
    for (int reg = 0; reg < 4; ++reg)
      bias[buf * 864 + (ro + qd * 4 + reg) * 18 + c] = (half_t)pw[reg];
  };

  // ---- priming: bias windows for t0 + K-frags for t0 ----
  {
    const int b0 = t0 & 1;
    f32x4 pw;
    pw = pe_window(t0 * 32 - 16); store_win(b0, 0, pw);
    pw = pe_window(t0 * 32);      store_win(b0, 16, pw);
    pw = pe_window(t0 * 32 + 16); store_win(b0, 32, pw); store_win(1 - b0, 0, pw);
  }
  half8 akc0, akc1, akc2, akc3;
  {
    const int n0 = m0 + t0 * 32;
    int kr0 = n0 + c;      if (kr0 > kKL - 1) kr0 = kKL - 1;
    int kr1 = n0 + 16 + c; if (kr1 > kKL - 1) kr1 = kKL - 1;
    akc0 = *(const half8*)(kb + (size_t)kr0 * kD + qd * 8);
    akc1 = *(const half8*)(kb + (size_t)kr0 * kD + 32 + qd * 8);
    akc2 = *(const half8*)(kb + (size_t)kr1 * kD + qd * 8);
    akc3 = *(const half8*)(kb + (size_t)kr1 * kD + 32 + qd * 8);
  }

  for (int t = t0; t < t1; ++t) {
    const int rel0 = t * 32;
    const int n0   = m0 + rel0;
    const int b    = t & 1;

    // ---- V A-frags (consumed last): V^T row dc*16+c, keys n0+h*16+qd*4.. ----
    half4 av[8];
#pragma unroll
    for (int dc = 0; dc < 4; ++dc)
#pragma unroll
      for (int h = 0; h < 2; ++h) {
        int nB = n0 + h * 16 + qd * 4; if (nB > kKL - 4) nB = kKL - 4;
        av[dc * 2 + h] = *(const half4*)(vt + (size_t)(dc * 16 + c) * kKL + nB);
      }

    // ---- bias reads for this tile (rows qd*4+reg-c+16, +16) ----
    float bb0[4], bb1[4];
#pragma unroll
    for (int reg = 0; reg < 4; ++reg) {
      const int ro = qd * 4 + reg - c + 16;     // in [1,31]
      bb0[reg] = (float)bias[b * 864 + ro * 18 + c];
      bb1[reg] = (float)bias[b * 864 + (ro + 16) * 18 + c];
    }

    // ---- prefetch next tile: K frags + 2 PE windows ----
    half8 akn0, akn1, akn2, akn3;
    const bool more = (t + 1 < t1);
    if (more) {
      const int n1 = n0 + 32;
      int kr0 = n1 + c;      if (kr0 > kKL - 1) kr0 = kKL - 1;
      int kr1 = n1 + 16 + c; if (kr1 > kKL - 1) kr1 = kKL - 1;
      akn0 = *(const half8*)(kb + (size_t)kr0 * kD + qd * 8);
      akn1 = *(const half8*)(kb + (size_t)kr0 * kD + 32 + qd * 8);
      akn2 = *(const half8*)(kb + (size_t)kr1 * kD + qd * 8);
      akn3 = *(const half8*)(kb + (size_t)kr1 * kD + 32 + qd * 8);
      f32x4 pw;
      pw = pe_window(rel0 + 32); store_win(1 - b, 16, pw);
      pw = pe_window(rel0 + 48); store_win(1 - b, 32, pw); store_win(b, 0, pw);
    }

    // ---- S^T = K.Q^T ----
    f32x4 s0 = {0,0,0,0}, s1 = {0,0,0,0};
    s0 = MFMA32(akc0, bq0, s0); s0 = MFMA32(akc1, bq1, s0);
    s1 = MFMA32(akc2, bq0, s1); s1 = MFMA32(akc3, bq1, s1);

    // ---- softmax (fixed C=0, exp2 domain) + ramp mask, P in registers ----
    float pm0[4], pm1[4];
#pragma unroll
    for (int reg = 0; reg < 4; ++reg) {
      const int kk = qd * 4 + reg;
      const int l0 = rel0 + kk - c;
      const int l1 = l0 + 16;
      const float e0 = (l0 >= 0 && l0 < kL) ? (s0[reg] + bb0[reg]) : -1e38f;
      const float e1 = (l1 >= 0 && l1 < kL) ? (s1[reg] + bb1[reg]) : -1e38f;
      const float p0 = __builtin_amdgcn_exp2f(e0);
      const float p1 = __builtin_amdgcn_exp2f(e1);
      const float mk0 = fminf(fmaxf(((float)l0 + cvl) * 0.015625f + 1.0f, 0.0f), 1.0f);
      const float mk1 = fminf(fmaxf(((float)l1 + cvl) * 0.015625f + 1.0f, 0.0f), 1.0f);
      pm0[reg] = p0 * mk0; pm1[reg] = p1 * mk1;
      zal += p0 + p1;
      zm  += pm0[reg] + pm1[reg];
    }
    const half4 pb0 = { (half_t)pm0[0], (half_t)pm0[1], (half_t)pm0[2], (half_t)pm0[3] };
    const half4 pb1 = { (half_t)pm1[0], (half_t)pm1[1], (half_t)pm1[2], (half_t)pm1[3] };

    // ---- PV: O^T[d][m] += V^T.P (8x mfma 16x16x16) ----
    o0 = MFMA16(av[0], pb0, o0); o0 = MFMA16(av[1], pb1, o0);
    o1 = MFMA16(av[2], pb0, o1); o1 = MFMA16(av[3], pb1, o1);
    o2 = MFMA16(av[4], pb0, o2); o2 = MFMA16(av[5], pb1, o2);
    o3 = MFMA16(av[6], pb0, o3); o3 = MFMA16(av[7], pb1, o3);

    if (more) { akc0 = akn0; akc1 = akn1; akc2 = akn2; akc3 = akn3; }
  }

  // ---- reduce z over the 4 qd replicas ----
  zal += __shfl_xor(zal, 16); zal += __shfl_xor(zal, 32);
  zm  += __shfl_xor(zm, 16);  zm  += __shfl_xor(zm, 32);

  float* mrgA = (float*)(smem + 8 * 4416);   // [8][16]
  float* mrgM = mrgA + 128;
  if (lane < 16) { mrgA[w * 16 + c] = zal; mrgM[w * 16 + c] = zm; }

  float* Ow = (float*)(smem + w * 4416);     // [m=16][d=68] f32, overlays bias
#pragma unroll
  for (int dc = 0; dc < 4; ++dc) {
    const f32x4 oo = (dc == 0) ? o0 : (dc == 1) ? o1 : (dc == 2) ? o2 : o3;
#pragma unroll
    for (int reg = 0; reg < 4; ++reg)
      Ow[c * 68 + dc * 16 + qd * 4 + reg] = oo[reg];
  }
  __syncthreads();

  // ---- 8-way merge + final normalize (exact reference semantics) ----
  const int dd = tid & 63;
  const int rb = tid >> 6;
#pragma unroll
  for (int rr = 0; rr < 2; ++rr) {
    const int r = rb * 2 + rr;
    float za = 0.0f, zmm = 0.0f, ov = 0.0f;
#pragma unroll
    for (int ww = 0; ww < 8; ++ww) {
      za  += mrgA[ww * 16 + r];
      zmm += mrgM[ww * 16 + r];
      ov  += ((float*)(smem + ww * 4416))[r * 68 + dd];
    }
    out[((size_t)bh * kM + m0 + r) * kD + dd] = ov / (zmm + 1e-8f * za);
  }
}

extern "C" void kernel_launch(void* const* d_in, const int* in_sizes, int n_in,
                              void* d_out, int out_size, void* d_ws, size_t ws_size,
                              hipStream_t stream) {
  (void)in_sizes; (void)n_in; (void)out_size; (void)ws_size;
  const float* q  = (const float*)d_in[0];
  const float* k  = (const float*)d_in[1];
  const float* v  = (const float*)d_in[2];
  const float* pe = (const float*)d_in[3];
  const float* cv = (const float*)d_in[4];
  half_t* ws = (half_t*)d_ws;   // needs 23,330,816 bytes
  float* out = (float*)d_out;

  prep_kernel<<<4384, 256, 0, stream>>>(q, k, v, pe, ws);
  attn_kernel<<<1024, 512, 0, stream>>>(ws, cv, out);
}

// Round 6
// 189.041 us; speedup vs baseline: 1.1186x; 1.1186x over previous
//
#include <hip/hip_runtime.h>

typedef _Float16 half_t;
typedef _Float16 half8 __attribute__((ext_vector_type(8)));
typedef _Float16 half4 __attribute__((ext_vector_type(4)));
typedef float f32x4 __attribute__((ext_vector_type(4)));

#define MFMA32(a, b, c) __builtin_amdgcn_mfma_f32_16x16x32_f16((a), (b), (c), 0, 0, 0)
#define MFMA16(a, b, c) __builtin_amdgcn_mfma_f32_16x16x16f16((a), (b), (c), 0, 0, 0)

static constexpr int kM  = 512;
static constexpr int kD  = 64;
static constexpr int kKL = 2560;
static constexpr int kL  = 2048;
// ws layout (halves): q_scaled | K f16 [bh][k][d] | Vc f16 chunked [bh][80][64][32] | peT f16 [l][d]
static constexpr int WS_QS  = 0;                    // 1,048,576
static constexpr int WS_KB  = 1048576;              // 5,242,880
static constexpr int WS_VC  = WS_KB + 5242880;      // 5,242,880
static constexpr int WS_PET = WS_VC + 5242880;      // 131,072

// ---------- K1 (fused): q/k convert + V chunked-transpose + pe transpose ----------
__global__ __launch_bounds__(256) void prep_kernel(const float* __restrict__ q,
    const float* __restrict__ k, const float* __restrict__ v,
    const float* __restrict__ pe, half_t* __restrict__ ws) {
  __shared__ float ls[64 * 72];
  const int b = blockIdx.x, t = threadIdx.x;
  if (b < 3072) {
    const int i = b * 256 + t;
    const float QS = 0.125f * 1.4426950408889634f;  // 1/sqrt(64) * log2(e)
    const float* src; half_t* dst; float sc;
    if (i < 131072) { src = q + (size_t)i * 8; dst = ws + WS_QS + (size_t)i * 8; sc = QS; }
    else { const int j = i - 131072; src = k + (size_t)j * 8; dst = ws + WS_KB + (size_t)j * 8; sc = 1.0f; }
    const float4 a = ((const float4*)src)[0];
    const float4 bb = ((const float4*)src)[1];
    half_t tt[8];
    tt[0] = (half_t)(a.x * sc);  tt[1] = (half_t)(a.y * sc);
    tt[2] = (half_t)(a.z * sc);  tt[3] = (half_t)(a.w * sc);
    tt[4] = (half_t)(bb.x * sc); tt[5] = (half_t)(bb.y * sc);
    tt[6] = (half_t)(bb.z * sc); tt[7] = (half_t)(bb.w * sc);
    *(int4*)dst = *(int4*)tt;
    return;
  }
  const bool isV = (b < 4352);
  int bh = 0, kt = 0, b3 = 0;
  const float* src; int sstride;
  if (isV) {
    const int b2 = b - 3072;
    bh = b2 / 40; kt = b2 % 40;                      // 64-key tile kt
    src = v + (size_t)(bh * 2560 + kt * 64) * 64; sstride = 64;
  } else {
    b3 = b - 4352;                                   // pe l-tile (64 l's)
    src = pe + (size_t)b3 * 64; sstride = 2048;
  }
  const int rr = t >> 4, cq = (t & 15) * 4;
#pragma unroll
  for (int p = 0; p < 4; ++p) {
    const float4 x = *(const float4*)(src + (size_t)(p * 16 + rr) * sstride + cq);
    *(float4*)(ls + (p * 16 + rr) * 72 + cq) = x;
  }
  __syncthreads();
  const int oc = t >> 2, ch = t & 3;
  half_t tmp[16];
#pragma unroll
  for (int i2 = 0; i2 < 16; ++i2) tmp[i2] = (half_t)ls[(ch * 16 + i2) * 72 + oc];
  half_t* o;
  if (isV) {
    // V^T chunk-major: Vc[bh][chunk=key/32][d=64][k=32]; here keys kt*64+ch*16+i2, d=oc
    o = ws + WS_VC + (size_t)bh * 163840 + ((kt << 1) + (ch >> 1)) * 2048 + oc * 32 + ((ch & 1) << 4);
  } else {
    // peT[l = b3*64+oc][d = ch*16 + i2]
    o = ws + WS_PET + ((size_t)b3 * 64 + oc) * 64 + ch * 16;
  }
  ((int4*)o)[0] = ((int4*)tmp)[0];
  ((int4*)o)[1] = ((int4*)tmp)[1];
}

// ---------- K2: fused banded attention, coalesced block staging ----------
// grid = 512 (32 bh x 16 m-blocks of 32 rows, XCD-swizzled), block = 128 (2 waves).
// Wave w owns m-rows [m0+16w, +16) COMPLETELY (no cross-wave merge).
// Both waves process key-chunk j = s at step s (65 steps). Per step the block
// cooperatively stages chunk s+1 of K (4KB), Vc (4KB), peT (4KB) with fully
// coalesced b128 loads into LDS rings (K,V depth 2; peT depth 4).
// S^T = K.Q^T (mfma 16x16x32); P stays in registers (B-frag of 16x16x16);
// bias realigned through a per-wave f32 strip [l&63][stride 18 dwords]
// (bank-conflict-free: 17c mod 32 distinct), windows carried across steps.
// LDS: K 2x4608 | peT 4x4608 @9216 | Vc 2x5120 @27648 | strips 2x4608 @37888 = 47104 B.
__global__ __launch_bounds__(128) void attn_kernel(
    const half_t* __restrict__ ws, const float* __restrict__ cvp,
    float* __restrict__ out) {

  __shared__ __align__(16) char smem[47104];
  half_t* lsh = (half_t*)smem;                 // half-granular view

  const int tid  = threadIdx.x;
  const int lane = tid & 63;
  const int w    = tid >> 6;                   // wave 0..1
  const int c    = lane & 15;
  const int qd   = lane >> 4;

  const int id = blockIdx.x;                   // 512 blocks
  const int bh = ((id & 7) << 2) | (id >> 7);  // XCD-aware: 4 bh per XCD
  const int mb = (id >> 3) & 15;
  const int m0 = mb << 5;                      // 32 query rows per block

  const float cvl = cvp[bh & 7] * 2048.0f - 2047.0f;  // mask = clamp((l+cvl)/64+1,0,1)

  const half_t* kb  = ws + WS_KB + (size_t)bh * (kKL * kD);
  const half_t* vcb = ws + WS_VC + (size_t)bh * (kKL * kD);
  const half_t* pet = ws + WS_PET;

  const int mrow = m0 + 16 * w + c;            // this lane's query row (c-col of MFMA)
  const half_t* qrow = ws + WS_QS + (size_t)(bh * kM + mrow) * kD;
  const half8 bq0 = *(const half8*)(qrow + qd * 8);
  const half8 bq1 = *(const half8*)(qrow + 32 + qd * 8);

  float* strip = (float*)(smem + 37888 + w * 4608);   // [row l&63][18 dwords]

  // staging registers (kept live across compute to overlap L2 latency)
  int4 stgK[2], stgP[2], stgV[2];
  auto issue = [&](int chk) {
#pragma unroll
    for (int u = 0; u < 2; ++u) {
      const int i = tid + (u << 7);            // 0..255 16B-units
      const int r = i >> 3, seg = i & 7;
      int krow = m0 + (chk << 5) + r; if (krow > kKL - 1) krow = kKL - 1;
      stgK[u] = *(const int4*)(kb + (size_t)krow * kD + seg * 8);
      int prow = (chk << 5) + r; if (prow > kL - 1) prow = kL - 1;
      stgP[u] = *(const int4*)(pet + (size_t)prow * kD + seg * 8);
      int vch = (m0 >> 5) + chk; if (vch > 79) vch = 79;
      stgV[u] = *(const int4*)(vcb + (size_t)vch * 2048 + i * 8);
    }
  };
  auto commit = [&](int chk) {
    const int sK = (chk & 1) * 2304;                   // halves
    const int sP = 4608 + (chk & 3) * 2304;
    const int sV = 13824 + (chk & 1) * 2560;
#pragma unroll
    for (int u = 0; u < 2; ++u) {
      const int i = tid + (u << 7);
      const int r = i >> 3, seg = i & 7;
      *(int4*)(lsh + sK + r * 72 + seg * 8) = stgK[u];
      *(int4*)(lsh + sP + r * 72 + seg * 8) = stgP[u];
      const int d = i >> 2, ks = (i & 3) * 8;
      *(int4*)(lsh + sV + d * 40 + ks) = stgV[u];
    }
  };

  issue(0); commit(0);
  __syncthreads();

  float zal = 0.0f, zm = 0.0f;
  f32x4 o0 = {0,0,0,0}, o1 = {0,0,0,0}, o2 = {0,0,0,0}, o3 = {0,0,0,0};
  const int lamw = -16 * w;                    // wave l-origin offset

  for (int s = 0; s <= 64; ++s) {
    if (s < 64) issue(s + 1);                  // loads in flight across compute

    const int lam = (s << 5) + lamw;           // l of chunk-local key 0 vs lane c=0
    const int sK  = (s & 1) * 2304;
    const int sV  = 13824 + (s & 1) * 2560;

    // ---- K A-frags from LDS ----
    const half8 ak00 = *(const half8*)(lsh + sK + c * 72 + qd * 8);
    const half8 ak01 = *(const half8*)(lsh + sK + c * 72 + 32 + qd * 8);
    const half8 ak10 = *(const half8*)(lsh + sK + (16 + c) * 72 + qd * 8);
    const half8 ak11 = *(const half8*)(lsh + sK + (16 + c) * 72 + 32 + qd * 8);

    // ---- 2 new PE bias windows -> strip (window at lam-16 persists from s-1) ----
#pragma unroll
    for (int win = 0; win < 2; ++win) {
      const int lbase = lam + (win << 4);
      int lc = lbase + c; lc = lc < 0 ? 0 : (lc > kL - 1 ? kL - 1 : lc);
      const int pb = 4608 + ((lc >> 5) & 3) * 2304 + (lc & 31) * 72;
      const half8 p0 = *(const half8*)(lsh + pb + qd * 8);
      const half8 p1 = *(const half8*)(lsh + pb + 32 + qd * 8);
      f32x4 acc = {0,0,0,0};
      acc = MFMA32(p0, bq0, acc);
      acc = MFMA32(p1, bq1, acc);
#pragma unroll
      for (int reg = 0; reg < 4; ++reg)
        strip[((lbase + qd * 4 + reg) & 63) * 18 + c] = acc[reg];
    }

    // ---- S^T = K.Q^T ----
    f32x4 s0 = {0,0,0,0}, s1 = {0,0,0,0};
    s0 = MFMA32(ak00, bq0, s0); s0 = MFMA32(ak01, bq1, s0);
    s1 = MFMA32(ak10, bq0, s1); s1 = MFMA32(ak11, bq1, s1);

    // ---- softmax (fixed C=0, exp2 domain) + ramp mask; P in registers ----
    float pm0[4], pm1[4];
#pragma unroll
    for (int reg = 0; reg < 4; ++reg) {
      const int kk = qd * 4 + reg;
      const int l0 = lam + kk - c, l1 = l0 + 16;
      const float b0 = strip[(l0 & 63) * 18 + c];
      const float b1 = strip[(l1 & 63) * 18 + c];
      const float e0 = (l0 >= 0 && l0 < kL) ? s0[reg] + b0 : -1e38f;
      const float e1 = (l1 >= 0 && l1 < kL) ? s1[reg] + b1 : -1e38f;
      const float p0 = __builtin_amdgcn_exp2f(e0);
      const float p1 = __builtin_amdgcn_exp2f(e1);
      const float mk0 = fminf(fmaxf(((float)l0 + cvl) * 0.015625f + 1.0f, 0.0f), 1.0f);
      const float mk1 = fminf(fmaxf(((float)l1 + cvl) * 0.015625f + 1.0f, 0.0f), 1.0f);
      pm0[reg] = p0 * mk0; pm1[reg] = p1 * mk1;
      zal += p0 + p1;
      zm  += pm0[reg] + pm1[reg];
    }
    const half4 pb0h = { (half_t)pm0[0], (half_t)pm0[1], (half_t)pm0[2], (half_t)pm0[3] };
    const half4 pb1h = { (half_t)pm1[0], (half_t)pm1[1], (half_t)pm1[2], (half_t)pm1[3] };

    // ---- PV: O^T[d][m] += V^T.P  (V A-frags from LDS, b64) ----
#pragma unroll
    for (int dc = 0; dc < 4; ++dc) {
      const half4 av0 = *(const half4*)(lsh + sV + (dc * 16 + c) * 40 + qd * 4);
      const half4 av1 = *(const half4*)(lsh + sV + (dc * 16 + c) * 40 + 16 + qd * 4);
      f32x4& od = (dc == 0) ? o0 : (dc == 1) ? o1 : (dc == 2) ? o2 : o3;
      od = MFMA16(av0, pb0h, od);
      od = MFMA16(av1, pb1h, od);
    }

    if (s < 64) commit(s + 1);                 // write staged chunk, then barrier
    __syncthreads();
  }

  // ---- normalize in-register (wave owns its rows; no cross-wave merge) ----
  zal += __shfl_xor(zal, 16); zal += __shfl_xor(zal, 32);
  zm  += __shfl_xor(zm, 16);  zm  += __shfl_xor(zm, 32);
  const float inv = 1.0f / (zm + 1e-8f * zal);

  float* op = out + ((size_t)bh * kM + mrow) * kD + qd * 4;
#pragma unroll
  for (int dc = 0; dc < 4; ++dc) {
    const f32x4 od = (dc == 0) ? o0 : (dc == 1) ? o1 : (dc == 2) ? o2 : o3;
    f32x4 r;
    r[0] = od[0] * inv; r[1] = od[1] * inv; r[2] = od[2] * inv; r[3] = od[3] * inv;
    *(f32x4*)(op + dc * 16) = r;
  }
}

extern "C" void kernel_launch(void* const* d_in, const int* in_sizes, int n_in,
                              void* d_out, int out_size, void* d_ws, size_t ws_size,
                              hipStream_t stream) {
  (void)in_sizes; (void)n_in; (void)out_size; (void)ws_size;
  const float* q  = (const float*)d_in[0];
  const float* k  = (const float*)d_in[1];
  const float* v  = (const float*)d_in[2];
  const float* pe = (const float*)d_in[3];
  const float* cv = (const float*)d_in[4];
  half_t* ws = (half_t*)d_ws;   // needs 23,330,816 bytes
  float* out = (float*)d_out;

  prep_kernel<<<4384, 256, 0, stream>>>(q, k, v, pe, ws);
  attn_kernel<<<512, 128, 0, stream>>>(ws, cv, out);
}

// Round 7
// 176.153 us; speedup vs baseline: 1.2005x; 1.0732x over previous
//
#include <hip/hip_runtime.h>

typedef _Float16 half_t;
typedef _Float16 half8 __attribute__((ext_vector_type(8)));
typedef _Float16 half4 __attribute__((ext_vector_type(4)));
typedef float f32x4 __attribute__((ext_vector_type(4)));

#define MFMA32(a, b, c) __builtin_amdgcn_mfma_f32_16x16x32_f16((a), (b), (c), 0, 0, 0)
#define MFMA16(a, b, c) __builtin_amdgcn_mfma_f32_16x16x16f16((a), (b), (c), 0, 0, 0)

static constexpr int kM  = 512;
static constexpr int kD  = 64;
static constexpr int kKL = 2560;
static constexpr int kL  = 2048;
// ws layout (halves): q_scaled | K f16 [bh][k][d] | Vc f16 chunked [bh][80][64][32] | peT f16 [l][d]
static constexpr int WS_QS  = 0;                    // 1,048,576
static constexpr int WS_KB  = 1048576;              // 5,242,880
static constexpr int WS_VC  = WS_KB + 5242880;      // 5,242,880
static constexpr int WS_PET = WS_VC + 5242880;      // 131,072

// ---------- K1 (fused): q/k convert + V chunked-transpose + pe transpose ----------
__global__ __launch_bounds__(256) void prep_kernel(const float* __restrict__ q,
    const float* __restrict__ k, const float* __restrict__ v,
    const float* __restrict__ pe, half_t* __restrict__ ws) {
  __shared__ float ls[64 * 72];
  const int b = blockIdx.x, t = threadIdx.x;
  if (b < 3072) {
    const int i = b * 256 + t;
    const float QS = 0.125f * 1.4426950408889634f;  // 1/sqrt(64) * log2(e)
    const float* src; half_t* dst; float sc;
    if (i < 131072) { src = q + (size_t)i * 8; dst = ws + WS_QS + (size_t)i * 8; sc = QS; }
    else { const int j = i - 131072; src = k + (size_t)j * 8; dst = ws + WS_KB + (size_t)j * 8; sc = 1.0f; }
    const float4 a = ((const float4*)src)[0];
    const float4 bb = ((const float4*)src)[1];
    half_t tt[8];
    tt[0] = (half_t)(a.x * sc);  tt[1] = (half_t)(a.y * sc);
    tt[2] = (half_t)(a.z * sc);  tt[3] = (half_t)(a.w * sc);
    tt[4] = (half_t)(bb.x * sc); tt[5] = (half_t)(bb.y * sc);
    tt[6] = (half_t)(bb.z * sc); tt[7] = (half_t)(bb.w * sc);
    *(int4*)dst = *(int4*)tt;
    return;
  }
  const bool isV = (b < 4352);
  int bh = 0, kt = 0, b3 = 0;
  const float* src; int sstride;
  if (isV) {
    const int b2 = b - 3072;
    bh = b2 / 40; kt = b2 % 40;                      // 64-key tile
    src = v + (size_t)(bh * 2560 + kt * 64) * 64; sstride = 64;
  } else {
    b3 = b - 4352;                                   // pe l-tile
    src = pe + (size_t)b3 * 64; sstride = 2048;
  }
  const int rr = t >> 4, cq = (t & 15) * 4;
#pragma unroll
  for (int p = 0; p < 4; ++p) {
    const float4 x = *(const float4*)(src + (size_t)(p * 16 + rr) * sstride + cq);
    *(float4*)(ls + (p * 16 + rr) * 72 + cq) = x;
  }
  __syncthreads();
  const int oc = t >> 2, ch = t & 3;
  half_t tmp[16];
#pragma unroll
  for (int i2 = 0; i2 < 16; ++i2) tmp[i2] = (half_t)ls[(ch * 16 + i2) * 72 + oc];
  half_t* o;
  if (isV) {
    // Vc[bh][chunk=key/32][d=64][k=32]; keys kt*64+ch*16+i2, d=oc
    o = ws + WS_VC + (size_t)bh * 163840 + ((kt << 1) + (ch >> 1)) * 2048 + oc * 32 + ((ch & 1) << 4);
  } else {
    o = ws + WS_PET + ((size_t)b3 * 64 + oc) * 64 + ch * 16;
  }
  ((int4*)o)[0] = ((int4*)tmp)[0];
  ((int4*)o)[1] = ((int4*)tmp)[1];
}

// ---------- K2: split-K in-block banded attention ----------
// grid = 512 (bh x 16 m-blocks of 32 rows), block = 256 = 2 pipelines x 2 waves.
// Pipeline p handles key-chunks g in [33p, 33p+33); chunk 65 self-masks (l>2047).
// Wave w2 of a pipeline owns m-rows [m0+16*w2, +16). Fixed-C softmax => partials
// merge by ADDITION: pipeline 1 deposits O/z in LDS, pipeline 0 finalizes.
// Per-pipeline coalesced staging (128 thr): K 4KB + peT 4KB + Vc 4KB per step,
// double-buffered; ONE barrier per step. Bias windows chunk-aligned (lbase=32g,
// w2-independent) so peT ring is depth 2; window at 32g-16 carried via strip.
// Per-pipeline LDS (33,536 B): K 2x4608 | peT 2x4608 | Vc 2x5120 | strip 2x2432 (f16 [64][19]).
// Total 67,072 B -> 2 blocks/CU = 8 waves/CU (2 waves/SIMD).
__global__ __launch_bounds__(256, 2) void attn_kernel(
    const half_t* __restrict__ ws, const float* __restrict__ cvp,
    float* __restrict__ out) {

  __shared__ __align__(16) char smem[67072];
  half_t* lsh = (half_t*)smem;

  const int tid  = threadIdx.x;
  const int lane = tid & 63;
  const int wv   = tid >> 6;       // 0..3
  const int pp   = wv >> 1;        // pipeline 0/1
  const int w2   = wv & 1;         // wave within pipeline
  const int c    = lane & 15;
  const int qd   = lane >> 4;
  const int ptid = tid & 127;      // thread id within pipeline

  const int id = blockIdx.x;                    // 512 blocks
  const int bh = ((id & 7) << 2) | (id >> 7);   // XCD-aware: 4 bh per XCD
  const int mb = (id >> 3) & 15;
  const int m0 = mb << 5;

  const float cvl = cvp[bh & 7] * 2048.0f - 2047.0f;  // mask = clamp((l+cvl)/64+1,0,1)

  const half_t* kb  = ws + WS_KB + (size_t)bh * (kKL * kD);
  const half_t* vcb = ws + WS_VC + (size_t)bh * (kKL * kD);
  const half_t* pet = ws + WS_PET;

  const int mrow = m0 + 16 * w2 + c;
  const half_t* qrow = ws + WS_QS + (size_t)(bh * kM + mrow) * kD;
  const half8 bq0 = *(const half8*)(qrow + qd * 8);
  const half8 bq1 = *(const half8*)(qrow + 32 + qd * 8);

  const int pbase = pp * 16768;                 // halves
  half_t* strip = lsh + pbase + 14336 + w2 * 1216;   // f16 [row l&63][stride 19]

  const int g0 = pp * 33;

  int4 stgK[2], stgP[2], stgV[2];
  auto issue = [&](int g) {
#pragma unroll
    for (int u = 0; u < 2; ++u) {
      const int i = ptid + (u << 7);           // 0..255 16B-units
      const int r = i >> 3, seg = i & 7;
      int krow = m0 + (g << 5) + r; if (krow > kKL - 1) krow = kKL - 1;
      stgK[u] = *(const int4*)(kb + (size_t)krow * kD + seg * 8);
      int prow = (g << 5) + r; if (prow > kL - 1) prow = kL - 1;
      stgP[u] = *(const int4*)(pet + (size_t)prow * kD + seg * 8);
      int vch = (m0 >> 5) + g; if (vch > 79) vch = 79;
      stgV[u] = *(const int4*)(vcb + (size_t)vch * 2048 + i * 8);
    }
  };
  auto commit = [&](int g) {
    const int sK = pbase + (g & 1) * 2304;
    const int sP = pbase + 4608 + (g & 1) * 2304;
    const int sV = pbase + 9216 + (g & 1) * 2560;
#pragma unroll
    for (int u = 0; u < 2; ++u) {
      const int i = ptid + (u << 7);
      const int r = i >> 3, seg = i & 7;
      *(int4*)(lsh + sK + r * 72 + seg * 8) = stgK[u];
      *(int4*)(lsh + sP + r * 72 + seg * 8) = stgP[u];
      const int d = i >> 2, ks = (i & 3) * 8;
      *(int4*)(lsh + sV + d * 40 + ks) = stgV[u];
    }
  };

  issue(g0);

  // ---- prime 2 boundary bias windows from GLOBAL peT (needed by pipeline 1;
  //      harmless garbage for pipeline 0 — those l are masked) ----
#pragma unroll
  for (int win = 0; win < 2; ++win) {
    const int lb = g0 * 32 - 32 + win * 16;
    int l = lb + c; l = l < 0 ? 0 : (l > kL - 1 ? kL - 1 : l);
    const half8 p0 = *(const half8*)(pet + (size_t)l * kD + qd * 8);
    const half8 p1 = *(const half8*)(pet + (size_t)l * kD + 32 + qd * 8);
    f32x4 acc = {0,0,0,0};
    acc = MFMA32(p0, bq0, acc);
    acc = MFMA32(p1, bq1, acc);
#pragma unroll
    for (int reg = 0; reg < 4; ++reg)
      strip[((lb + qd * 4 + reg) & 63) * 19 + c] = (half_t)acc[reg];
  }

  commit(g0);
  __syncthreads();

  float zal = 0.0f, zm = 0.0f;
  f32x4 o0 = {0,0,0,0}, o1 = {0,0,0,0}, o2 = {0,0,0,0}, o3 = {0,0,0,0};

  for (int t = 0; t <= 32; ++t) {
    const int g = g0 + t;
    if (t < 32) issue(g + 1);

    const int lam = (g << 5) - 16 * w2;
    const int sK  = pbase + (g & 1) * 2304;
    const int sP  = pbase + 4608 + (g & 1) * 2304;
    const int sV  = pbase + 9216 + (g & 1) * 2560;

    // ---- K A-frags from LDS ----
    const half8 ak00 = *(const half8*)(lsh + sK + c * 72 + qd * 8);
    const half8 ak01 = *(const half8*)(lsh + sK + c * 72 + 32 + qd * 8);
    const half8 ak10 = *(const half8*)(lsh + sK + (16 + c) * 72 + qd * 8);
    const half8 ak11 = *(const half8*)(lsh + sK + (16 + c) * 72 + 32 + qd * 8);

    // ---- 2 chunk-aligned bias windows (lbase = 32g, 32g+16) -> strip ----
#pragma unroll
    for (int win = 0; win < 2; ++win) {
      const int lbase = (g << 5) + (win << 4);
      const int ro = (win << 4) + c;           // row within current peT chunk
      const half8 p0 = *(const half8*)(lsh + sP + ro * 72 + qd * 8);
      const half8 p1 = *(const half8*)(lsh + sP + ro * 72 + 32 + qd * 8);
      f32x4 acc = {0,0,0,0};
      acc = MFMA32(p0, bq0, acc);
      acc = MFMA32(p1, bq1, acc);
#pragma unroll
      for (int reg = 0; reg < 4; ++reg)
        strip[((lbase + qd * 4 + reg) & 63) * 19 + c] = (half_t)acc[reg];
    }

    // ---- S^T = K.Q^T ----
    f32x4 s0 = {0,0,0,0}, s1 = {0,0,0,0};
    s0 = MFMA32(ak00, bq0, s0); s0 = MFMA32(ak01, bq1, s0);
    s1 = MFMA32(ak10, bq0, s1); s1 = MFMA32(ak11, bq1, s1);

    // ---- softmax (fixed C=0, exp2 domain) + ramp mask; P in registers ----
    float pm0[4], pm1[4];
#pragma unroll
    for (int reg = 0; reg < 4; ++reg) {
      const int kk = qd * 4 + reg;
      const int l0 = lam + kk - c, l1 = l0 + 16;
      const float b0 = (float)strip[(l0 & 63) * 19 + c];
      const float b1 = (float)strip[(l1 & 63) * 19 + c];
      const float e0 = (l0 >= 0 && l0 < kL) ? s0[reg] + b0 : -1e38f;
      const float e1 = (l1 >= 0 && l1 < kL) ? s1[reg] + b1 : -1e38f;
      const float p0 = __builtin_amdgcn_exp2f(e0);
      const float p1 = __builtin_amdgcn_exp2f(e1);
      const float mk0 = fminf(fmaxf(((float)l0 + cvl) * 0.015625f + 1.0f, 0.0f), 1.0f);
      const float mk1 = fminf(fmaxf(((float)l1 + cvl) * 0.015625f + 1.0f, 0.0f), 1.0f);
      pm0[reg] = p0 * mk0; pm1[reg] = p1 * mk1;
      zal += p0 + p1;
      zm  += pm0[reg] + pm1[reg];
    }
    const half4 pb0h = { (half_t)pm0[0], (half_t)pm0[1], (half_t)pm0[2], (half_t)pm0[3] };
    const half4 pb1h = { (half_t)pm1[0], (half_t)pm1[1], (half_t)pm1[2], (half_t)pm1[3] };

    // ---- PV: O^T[d][m] += V^T.P ----
#pragma unroll
    for (int dc = 0; dc < 4; ++dc) {
      const half4 av0 = *(const half4*)(lsh + sV + (dc * 16 + c) * 40 + qd * 4);
      const half4 av1 = *(const half4*)(lsh + sV + (dc * 16 + c) * 40 + 16 + qd * 4);
      f32x4& od = (dc == 0) ? o0 : (dc == 1) ? o1 : (dc == 2) ? o2 : o3;
      od = MFMA16(av0, pb0h, od);
      od = MFMA16(av1, pb1h, od);
    }

    if (t < 32) commit(g + 1);
    __syncthreads();
  }

  // ---- reduce z over qd replicas ----
  zal += __shfl_xor(zal, 16); zal += __shfl_xor(zal, 32);
  zm  += __shfl_xor(zm, 16);  zm  += __shfl_xor(zm, 32);

  // ---- cross-pipeline merge (pure addition; overlays pipeline-1 K/peT rings) ----
  float* mO = (float*)smem + 8384;             // [w2][d=64][stride 17] f32
  float* mZ = (float*)smem + 10560;            // zal[32] | zm[32]
  __syncthreads();
  if (pp == 1) {
#pragma unroll
    for (int dc = 0; dc < 4; ++dc) {
      const f32x4 od = (dc == 0) ? o0 : (dc == 1) ? o1 : (dc == 2) ? o2 : o3;
#pragma unroll
      for (int reg = 0; reg < 4; ++reg)
        mO[w2 * 1088 + (dc * 16 + qd * 4 + reg) * 17 + c] = od[reg];
    }
    if (lane < 16) { mZ[w2 * 16 + c] = zal; mZ[32 + w2 * 16 + c] = zm; }
  }
  __syncthreads();
  if (pp == 0) {
    const float za2 = zal + mZ[w2 * 16 + c];
    const float zm2 = zm + mZ[32 + w2 * 16 + c];
    const float inv = 1.0f / (zm2 + 1e-8f * za2);
    float* op = out + ((size_t)bh * kM + mrow) * kD + qd * 4;
#pragma unroll
    for (int dc = 0; dc < 4; ++dc) {
      const f32x4 od = (dc == 0) ? o0 : (dc == 1) ? o1 : (dc == 2) ? o2 : o3;
      f32x4 r;
#pragma unroll
      for (int reg = 0; reg < 4; ++reg)
        r[reg] = (od[reg] + mO[w2 * 1088 + (dc * 16 + qd * 4 + reg) * 17 + c]) * inv;
      *(f32x4*)(op + dc * 16) = r;
    }
  }
}

extern "C" void kernel_launch(void* const* d_in, const int* in_sizes, int n_in,
                              void* d_out, int out_size, void* d_ws, size_t ws_size,
                              hipStream_t stream) {
  (void)in_sizes; (void)n_in; (void)out_size; (void)ws_size;
  const float* q  = (const float*)d_in[0];
  const float* k  = (const float*)d_in[1];
  const float* v  = (const float*)d_in[2];
  const float* pe = (const float*)d_in[3];
  const float* cv = (const float*)d_in[4];
  half_t* ws = (half_t*)d_ws;   // needs 23,330,816 bytes
  float* out = (float*)d_out;

  prep_kernel<<<4384, 256, 0, stream>>>(q, k, v, pe, ws);
  attn_kernel<<<512, 256, 0, stream>>>(ws, cv, out);
}

// Round 8
// 175.542 us; speedup vs baseline: 1.2047x; 1.0035x over previous
//
#include <hip/hip_runtime.h>

typedef _Float16 half_t;
typedef _Float16 half8 __attribute__((ext_vector_type(8)));
typedef _Float16 half4 __attribute__((ext_vector_type(4)));
typedef float f32x4 __attribute__((ext_vector_type(4)));

#define MFMA32(a, b, c) __builtin_amdgcn_mfma_f32_16x16x32_f16((a), (b), (c), 0, 0, 0)
#define MFMA16(a, b, c) __builtin_amdgcn_mfma_f32_16x16x16f16((a), (b), (c), 0, 0, 0)

static constexpr int kM  = 512;
static constexpr int kD  = 64;
static constexpr int kKL = 2560;
static constexpr int kL  = 2048;
// ws (halves): q_scaled | K [bh][k][d] | Vc chunked [bh][80][64][32] | peT [l][d] | z (f32)
static constexpr int WS_QS  = 0;                    // 1,048,576
static constexpr int WS_KB  = 1048576;              // 5,242,880
static constexpr int WS_VC  = WS_KB + 5242880;      // 5,242,880
static constexpr int WS_PET = WS_VC + 5242880;      // 131,072
static constexpr int WS_Z   = WS_PET + 131072;      // 2*16384 f32 = 131,072 B
// ws bytes needed: 23,461,888

// ---------- K1: q/k convert + V chunked-transpose + pe transpose + zero out/z ----------
__global__ __launch_bounds__(256) void prep_kernel(const float* __restrict__ q,
    const float* __restrict__ k, const float* __restrict__ v,
    const float* __restrict__ pe, half_t* __restrict__ ws, float* __restrict__ out) {
  __shared__ float ls[64 * 72];
  const int b = blockIdx.x, t = threadIdx.x;
  if (b < 3072) {
    const int i = b * 256 + t;
    const float QS = 0.125f * 1.4426950408889634f;  // 1/sqrt(64) * log2(e)
    const float* src; half_t* dst; float sc;
    if (i < 131072) { src = q + (size_t)i * 8; dst = ws + WS_QS + (size_t)i * 8; sc = QS; }
    else { const int j = i - 131072; src = k + (size_t)j * 8; dst = ws + WS_KB + (size_t)j * 8; sc = 1.0f; }
    const float4 a = ((const float4*)src)[0];
    const float4 bb = ((const float4*)src)[1];
    half_t tt[8];
    tt[0] = (half_t)(a.x * sc);  tt[1] = (half_t)(a.y * sc);
    tt[2] = (half_t)(a.z * sc);  tt[3] = (half_t)(a.w * sc);
    tt[4] = (half_t)(bb.x * sc); tt[5] = (half_t)(bb.y * sc);
    tt[6] = (half_t)(bb.z * sc); tt[7] = (half_t)(bb.w * sc);
    *(int4*)dst = *(int4*)tt;
    return;
  }
  if (b >= 4384) {
    if (b < 4640) {                       // zero d_out (1,048,576 f32)
      float4* o = (float4*)out;
      const int base = (b - 4384) * 1024 + t;
#pragma unroll
      for (int u = 0; u < 4; ++u) o[base + u * 256] = float4{0, 0, 0, 0};
    } else {                              // zero z (32,768 f32)
      float4* z = (float4*)((float*)(ws + WS_Z));
      const int base = (b - 4640) * 1024 + t;
#pragma unroll
      for (int u = 0; u < 4; ++u) z[base + u * 256] = float4{0, 0, 0, 0};
    }
    return;
  }
  const bool isV = (b < 4352);
  int bh = 0, kt = 0, b3 = 0;
  const float* src; int sstride;
  if (isV) {
    const int b2 = b - 3072;
    bh = b2 / 40; kt = b2 % 40;
    src = v + (size_t)(bh * 2560 + kt * 64) * 64; sstride = 64;
  } else {
    b3 = b - 4352;
    src = pe + (size_t)b3 * 64; sstride = 2048;
  }
  const int rr = t >> 4, cq = (t & 15) * 4;
#pragma unroll
  for (int p = 0; p < 4; ++p) {
    const float4 x = *(const float4*)(src + (size_t)(p * 16 + rr) * sstride + cq);
    *(float4*)(ls + (p * 16 + rr) * 72 + cq) = x;
  }
  __syncthreads();
  const int oc = t >> 2, ch = t & 3;
  half_t tmp[16];
#pragma unroll
  for (int i2 = 0; i2 < 16; ++i2) tmp[i2] = (half_t)ls[(ch * 16 + i2) * 72 + oc];
  half_t* o;
  if (isV) {
    o = ws + WS_VC + (size_t)bh * 163840 + ((kt << 1) + (ch >> 1)) * 2048 + oc * 32 + ((ch & 1) << 4);
  } else {
    o = ws + WS_PET + ((size_t)b3 * 64 + oc) * 64 + ch * 16;
  }
  ((int4*)o)[0] = ((int4*)tmp)[0];
  ((int4*)o)[1] = ((int4*)tmp)[1];
}

// ---------- K2: fat-wave split-K banded attention ----------
// grid 512 = 32bh x 4 m-blocks(128 rows) x 4 K-splits; block 128 (2 waves).
// Wave w2 owns rows m0+64*w2..+63 as 4 MFMA m-frags (4 independent softmax
// chains for ILP). Both waves share block-staged K chunk (4KB) + Vc chunk
// (4KB) per step, double-buffered, ONE barrier/step, 17 steps (68 chunks /4).
// S^T = K.Q^T; P stays in registers (B-frag of 16x16x16); PE bias MFMA'd into
// per-frag f32 rings [64][19] (A-frags shared across adjacent frags: 5 loads).
// Fixed-C softmax => split partials merge by addition: atomicAdd into zeroed
// d_out + z arrays; norm_kernel divides afterwards.
__global__ __launch_bounds__(128, 2) void attn_kernel(
    const half_t* __restrict__ ws, const float* __restrict__ cvp,
    float* __restrict__ out, float* __restrict__ zalA, float* __restrict__ zmA) {

  __shared__ __align__(16) char smem[58368];
  half_t* lsh = (half_t*)smem;

  const int tid  = threadIdx.x;
  const int lane = tid & 63;
  const int w2   = tid >> 6;
  const int c    = lane & 15;
  const int qd   = lane >> 4;

  const int id = blockIdx.x;                    // 512
  const int bh = ((id & 7) << 2) | (id >> 7);   // XCD-aware: 4 bh per XCD
  const int mid = (id >> 3) & 15;
  const int mb = mid & 3, sp = mid >> 2;
  const int m0 = mb << 7;                       // 128 rows per block
  const int g0 = sp * 17;                       // chunks [g0, g0+17)

  const float cvl = cvp[bh & 7] * 2048.0f - 2047.0f;  // mask = clamp((l+cvl)/64+1,0,1)

  const half_t* kb  = ws + WS_KB + (size_t)bh * (kKL * kD);
  const half_t* vcb = ws + WS_VC + (size_t)bh * (kKL * kD);
  const half_t* pet = ws + WS_PET;

  // Q B-frags for the wave's 4 m-frags
  half8 bq0[4], bq1[4];
#pragma unroll
  for (int f = 0; f < 4; ++f) {
    const half_t* qrow = ws + WS_QS + (size_t)(bh * kM + m0 + 64 * w2 + 16 * f + c) * kD;
    bq0[f] = *(const half8*)(qrow + qd * 8);
    bq1[f] = *(const half8*)(qrow + 32 + qd * 8);
  }

  // LDS map (bytes): K ring 2x4608 @0 | Vc ring 2x5120 @9216 | strips 8x4864 @19456
  float* strip = (float*)(smem + 19456) + (size_t)w2 * 4864;  // 4 frag rings [64][19] f32

  int4 stgK[2], stgV[2];
  auto issue = [&](int g) {
#pragma unroll
    for (int u = 0; u < 2; ++u) {
      const int i = tid + (u << 7);            // 0..255 16B-units
      const int r = i >> 3, seg = i & 7;
      int krow = m0 + (g << 5) + r; if (krow > kKL - 1) krow = kKL - 1;
      stgK[u] = *(const int4*)(kb + (size_t)krow * kD + seg * 8);
      int vch = (m0 >> 5) + g; if (vch > 79) vch = 79;
      stgV[u] = *(const int4*)(vcb + (size_t)vch * 2048 + i * 8);
    }
  };
  auto commit = [&](int g) {
    const int sK = (g & 1) * 2304;             // halves
    const int sV = 4608 + (g & 1) * 2560;
#pragma unroll
    for (int u = 0; u < 2; ++u) {
      const int i = tid + (u << 7);
      const int r = i >> 3, seg = i & 7;
      *(int4*)(lsh + sK + r * 72 + seg * 8) = stgK[u];
      const int d = i >> 2, ks = (i & 3) * 8;
      *(int4*)(lsh + sV + d * 40 + ks) = stgV[u];
    }
  };

  issue(g0);
  // prime one bias window per frag (covers l in [base_f-16, base_f))
#pragma unroll
  for (int f = 0; f < 4; ++f) {
    const int wb = (g0 << 5) - 64 * w2 - 16 * f - 16;
    int l = wb + c; l = l < 0 ? 0 : (l > kL - 1 ? kL - 1 : l);
    const half8 p0 = *(const half8*)(pet + (size_t)l * kD + qd * 8);
    const half8 p1 = *(const half8*)(pet + (size_t)l * kD + 32 + qd * 8);
    f32x4 a = {0, 0, 0, 0};
    a = MFMA32(p0, bq0[f], a);
    a = MFMA32(p1, bq1[f], a);
    float* stf = strip + f * 1216;
#pragma unroll
    for (int reg = 0; reg < 4; ++reg)
      stf[((wb + qd * 4 + reg) & 63) * 19 + c] = a[reg];
  }
  commit(g0);
  __syncthreads();

  float zac[4] = {0, 0, 0, 0}, zmc[4] = {0, 0, 0, 0};
  f32x4 o[4][4];
#pragma unroll
  for (int f = 0; f < 4; ++f)
#pragma unroll
    for (int dc = 0; dc < 4; ++dc) o[f][dc] = f32x4{0, 0, 0, 0};

  for (int t = 0; t < 17; ++t) {
    const int g = g0 + t;
    if (t < 16) issue(g + 1);

    const int sK = (g & 1) * 2304;
    const int sV = 4608 + (g & 1) * 2560;

    // K A-frags (shared by all m-frags)
    const half8 ak00 = *(const half8*)(lsh + sK + c * 72 + qd * 8);
    const half8 ak01 = *(const half8*)(lsh + sK + c * 72 + 32 + qd * 8);
    const half8 ak10 = *(const half8*)(lsh + sK + (16 + c) * 72 + qd * 8);
    const half8 ak11 = *(const half8*)(lsh + sK + (16 + c) * 72 + 32 + qd * 8);
    // V^T A-frags (shared)
    half4 av[8];
#pragma unroll
    for (int dc = 0; dc < 4; ++dc)
#pragma unroll
      for (int kg = 0; kg < 2; ++kg)
        av[dc * 2 + kg] = *(const half4*)(lsh + sV + (dc * 16 + c) * 40 + kg * 16 + qd * 4);

    // PE bias: 5 shared A-frag windows -> per-frag strips (2 windows/frag)
    const int bB = (g << 5) - 64 * w2;
#pragma unroll
    for (int k5 = 0; k5 < 5; ++k5) {
      const int wb = bB + 16 - (k5 << 4);
      int l = wb + c; l = l < 0 ? 0 : (l > kL - 1 ? kL - 1 : l);
      const half8 p0 = *(const half8*)(pet + (size_t)l * kD + qd * 8);
      const half8 p1 = *(const half8*)(pet + (size_t)l * kD + 32 + qd * 8);
      if (k5 < 4) {
        f32x4 a = {0, 0, 0, 0};
        a = MFMA32(p0, bq0[k5], a);
        a = MFMA32(p1, bq1[k5], a);
        float* stf = strip + k5 * 1216;
#pragma unroll
        for (int reg = 0; reg < 4; ++reg)
          stf[((wb + qd * 4 + reg) & 63) * 19 + c] = a[reg];
      }
      if (k5 >= 1) {
        f32x4 a = {0, 0, 0, 0};
        a = MFMA32(p0, bq0[k5 - 1], a);
        a = MFMA32(p1, bq1[k5 - 1], a);
        float* stf = strip + (k5 - 1) * 1216;
#pragma unroll
        for (int reg = 0; reg < 4; ++reg)
          stf[((wb + qd * 4 + reg) & 63) * 19 + c] = a[reg];
      }
    }

    // per-frag: S^T, softmax, PV (4 independent chains)
#pragma unroll
    for (int f = 0; f < 4; ++f) {
      f32x4 s0 = {0, 0, 0, 0}, s1 = {0, 0, 0, 0};
      s0 = MFMA32(ak00, bq0[f], s0); s0 = MFMA32(ak01, bq1[f], s0);
      s1 = MFMA32(ak10, bq0[f], s1); s1 = MFMA32(ak11, bq1[f], s1);

      const int base_f = bB - 16 * f;
      const float* stf = strip + f * 1216;
      const bool interior = (base_f >= 16 && base_f <= 2016);
      float pm0[4], pm1[4];
#pragma unroll
      for (int reg = 0; reg < 4; ++reg) {
        const int l0 = base_f + qd * 4 + reg - c;
        const int l1 = l0 + 16;
        const float b0 = stf[(l0 & 63) * 19 + c];
        const float b1 = stf[(l1 & 63) * 19 + c];
        float e0, e1;
        if (interior) { e0 = s0[reg] + b0; e1 = s1[reg] + b1; }
        else {
          e0 = (l0 >= 0 && l0 < kL) ? s0[reg] + b0 : -1e38f;
          e1 = (l1 >= 0 && l1 < kL) ? s1[reg] + b1 : -1e38f;
        }
        const float p0 = __builtin_amdgcn_exp2f(e0);
        const float p1 = __builtin_amdgcn_exp2f(e1);
        const float mk0 = fminf(fmaxf(((float)l0 + cvl) * 0.015625f + 1.0f, 0.0f), 1.0f);
        const float mk1 = fminf(fmaxf(((float)l1 + cvl) * 0.015625f + 1.0f, 0.0f), 1.0f);
        pm0[reg] = p0 * mk0; pm1[reg] = p1 * mk1;
        zac[f] += p0 + p1;
        zmc[f] += pm0[reg] + pm1[reg];
      }
      const half4 pb0h = { (half_t)pm0[0], (half_t)pm0[1], (half_t)pm0[2], (half_t)pm0[3] };
      const half4 pb1h = { (half_t)pm1[0], (half_t)pm1[1], (half_t)pm1[2], (half_t)pm1[3] };
#pragma unroll
      for (int dc = 0; dc < 4; ++dc) {
        o[f][dc] = MFMA16(av[dc * 2 + 0], pb0h, o[f][dc]);
        o[f][dc] = MFMA16(av[dc * 2 + 1], pb1h, o[f][dc]);
      }
    }

    if (t < 16) commit(g + 1);
    __syncthreads();
  }

  // ---- epilogue: z atomics + O via LDS transpose + coalesced atomicAdd ----
  __syncthreads();                             // all compute done; safe to overlay
  float* Ow = (float*)smem + (size_t)w2 * 4352;   // [64 rows][stride 68] f32
#pragma unroll
  for (int f = 0; f < 4; ++f)
#pragma unroll
    for (int dc = 0; dc < 4; ++dc)
      *(f32x4*)(Ow + (16 * f + c) * 68 + dc * 16 + qd * 4) = o[f][dc];

#pragma unroll
  for (int f = 0; f < 4; ++f) {
    float a = zac[f], m = zmc[f];
    a += __shfl_xor(a, 16); a += __shfl_xor(a, 32);
    m += __shfl_xor(m, 16); m += __shfl_xor(m, 32);
    if (lane < 16) {
      const int row = bh * kM + m0 + 64 * w2 + 16 * f + c;
      atomicAdd(&zalA[row], a);
      atomicAdd(&zmA[row], m);
    }
  }
  const int rowbase = bh * kM + m0 + 64 * w2;
  for (int rr = 0; rr < 64; ++rr)
    atomicAdd(out + (size_t)(rowbase + rr) * kD + lane, Ow[rr * 68 + lane]);
}

// ---------- K3: normalize ----------
__global__ __launch_bounds__(256) void norm_kernel(const float* __restrict__ zalA,
    const float* __restrict__ zmA, float* __restrict__ out) {
  const int i = blockIdx.x * 256 + threadIdx.x;   // 262,144
  const int row = i >> 4, d4 = (i & 15) << 2;
  const float inv = 1.0f / (zmA[row] + 1e-8f * zalA[row]);
  float4* p = (float4*)(out + (size_t)row * 64 + d4);
  float4 v = *p;
  v.x *= inv; v.y *= inv; v.z *= inv; v.w *= inv;
  *p = v;
}

extern "C" void kernel_launch(void* const* d_in, const int* in_sizes, int n_in,
                              void* d_out, int out_size, void* d_ws, size_t ws_size,
                              hipStream_t stream) {
  (void)in_sizes; (void)n_in; (void)out_size; (void)ws_size;
  const float* q  = (const float*)d_in[0];
  const float* k  = (const float*)d_in[1];
  const float* v  = (const float*)d_in[2];
  const float* pe = (const float*)d_in[3];
  const float* cv = (const float*)d_in[4];
  half_t* ws = (half_t*)d_ws;   // needs 23,461,888 bytes
  float* out = (float*)d_out;
  float* zalA = (float*)(ws + WS_Z);
  float* zmA  = zalA + 16384;

  prep_kernel<<<4648, 256, 0, stream>>>(q, k, v, pe, ws, out);
  attn_kernel<<<512, 128, 0, stream>>>(ws, cv, out, zalA, zmA);
  norm_kernel<<<1024, 256, 0, stream>>>(zalA, zmA, out);
}